// Round 6
// baseline (1163.337 us; speedup 1.0000x reference)
//
#include <hip/hip_runtime.h>
#include <hip/hip_cooperative_groups.h>
#include <stdint.h>

namespace cg = cooperative_groups;
typedef unsigned long long u64;
typedef float nfloat4 __attribute__((ext_vector_type(4)));  // native vec for nontemporal builtins

// ---------------------------------------------------------------------------
// Binarized GraphSAGE, 2 layers. Round-6: cooperative single-kernel fusion,
// hardened after round-5's silent failure (absmax ~= max|ref| => output never
// written => cooperative launch most likely REJECTED and unchecked):
//   * grid 512 blocks @ __launch_bounds__(256,2) -> 2 blocks/CU co-residency,
//     safely under any occupancy computation (was 1024 @ 4/CU, marginal).
//   * explicit __threadfence() before AND after every grid.sync() (agent-scope
//     release/acquire: L2 writeback + L1 invalidate; per-XCD L2s are not
//     coherent and grid.sync alone may not emit the full cache ops).
//   * hipLaunchCooperativeKernel return code CHECKED; on any error fall back
//     to the round-4 verified 5-dispatch chain (identical phase bodies via
//     shared __device__ functions) — correctness never depends on coop launch.
// Phases (grid-stride, any grid size correct):
//   A: weight packs + zero cnt/mark | B: direct-slot scatter + mark
//   C: bin_act(x) marked rows (8 rows/wave, NT loads) | D: layer1 | E: layer2
//
// Bit layout for 128-wide rows (x rows AND layer1 weight rows — must match;
// guaranteed by sharing pack_row128):
//   element e = (it*8+c)*4+k  ->  word (c>>2), bit 16*(c&3) + it*4 + k
// 256-wide rows (h rows and layer2 weight rows): word (e>>6), bit (e&63).
// ---------------------------------------------------------------------------

#define CAP1 128
#define CAP2 128
#define NBLK 512
#define NTHR 256

struct Params {
  const float* x;
  const int *src1, *dst1, *src2, *dst2;
  const float *w_rel1, *b_rel1, *w_root1, *b_root1;
  const float *w_rel2, *b_rel2, *w_root2, *b_root2;
  u64* rec;                 // [N0] stride 32B: {b0,b1, alpha, pad}
  u64* bits2; float* alpha2;
  int *slots1, *slots2, *cnt1, *cnt2;
  unsigned char* mark;
  ulonglong2 *wbr1, *wbt1;
  u64 *wbr2, *wbt2;
  float *m_r1, *m_t1, *m_r2, *m_t2;
  float* out;
  int E1, E2, N0, N1, N2;
};

// sign-pack one 128-elem row held by an 8-lane group (16 elems/lane), vs mu.
__device__ __forceinline__ void pack_row128(
    float4 v0, float4 v1, float4 v2, float4 v3, float mu, int c,
    u64& w0, u64& w1)
{
  unsigned m = 0;
  m |= (v0.x > mu) ? 1u << 0  : 0u;
  m |= (v0.y > mu) ? 1u << 1  : 0u;
  m |= (v0.z > mu) ? 1u << 2  : 0u;
  m |= (v0.w > mu) ? 1u << 3  : 0u;
  m |= (v1.x > mu) ? 1u << 4  : 0u;
  m |= (v1.y > mu) ? 1u << 5  : 0u;
  m |= (v1.z > mu) ? 1u << 6  : 0u;
  m |= (v1.w > mu) ? 1u << 7  : 0u;
  m |= (v2.x > mu) ? 1u << 8  : 0u;
  m |= (v2.y > mu) ? 1u << 9  : 0u;
  m |= (v2.z > mu) ? 1u << 10 : 0u;
  m |= (v2.w > mu) ? 1u << 11 : 0u;
  m |= (v3.x > mu) ? 1u << 12 : 0u;
  m |= (v3.y > mu) ? 1u << 13 : 0u;
  m |= (v3.z > mu) ? 1u << 14 : 0u;
  m |= (v3.w > mu) ? 1u << 15 : 0u;
  u64 wv = (u64)m << (16 * (c & 3));
  wv |= __shfl_xor(wv, 1);
  wv |= __shfl_xor(wv, 2);
  u64 other = __shfl_xor(wv, 4);
  w0 = (c & 4) ? other : wv;
  w1 = (c & 4) ? wv : other;
}

// pack a 128-wide weight block of rows (8 rows per wave), same layout
__device__ __forceinline__ void prep_w128_block(
    const float* __restrict__ w, int rowbase, int tid,
    ulonglong2* __restrict__ wbits, float* __restrict__ m)
{
  int lane = tid & 63;
  int g = lane >> 3, c = lane & 7;
  int row = rowbase + (tid >> 6) * 8 + g;
  const float4* wr = (const float4*)(w + (size_t)row * 128);
  float4 v0 = wr[c];
  float4 v1 = wr[c + 8];
  float4 v2 = wr[c + 16];
  float4 v3 = wr[c + 24];
  float s = fabsf(v0.x) + fabsf(v0.y) + fabsf(v0.z) + fabsf(v0.w)
          + fabsf(v1.x) + fabsf(v1.y) + fabsf(v1.z) + fabsf(v1.w)
          + fabsf(v2.x) + fabsf(v2.y) + fabsf(v2.z) + fabsf(v2.w)
          + fabsf(v3.x) + fabsf(v3.y) + fabsf(v3.z) + fabsf(v3.w);
  s += __shfl_xor(s, 1); s += __shfl_xor(s, 2); s += __shfl_xor(s, 4);
  u64 w0, w1;
  pack_row128(v0, v1, v2, v3, 0.0f, c, w0, w1);
  if (c == 0) {
    wbits[row] = make_ulonglong2(w0, w1);
    m[row] = s * (1.0f / 128.0f);
  }
}

// pack a 256-wide weight block (1 row per wave, 4 rows per 256-thr block)
__device__ __forceinline__ void prep_w256_block(
    const float* __restrict__ w, int rowbase, int tid,
    u64* __restrict__ wbits, float* __restrict__ m)
{
  int lane = tid & 63;
  int o = rowbase + (tid >> 6);
  const float* wr = w + (size_t)o * 256;
  float s = 0.0f;
  u64 b[4];
  #pragma unroll
  for (int wd = 0; wd < 4; wd++) {
    float v = wr[wd * 64 + lane];
    s += fabsf(v);
    b[wd] = __ballot(v > 0.0f);
  }
  #pragma unroll
  for (int off = 32; off > 0; off >>= 1) s += __shfl_xor(s, off);
  if (lane == 0) {
    wbits[o * 4 + 0] = b[0]; wbits[o * 4 + 1] = b[1];
    wbits[o * 4 + 2] = b[2]; wbits[o * 4 + 3] = b[3];
    m[o] = s * (1.0f / 256.0f);
  }
}

// ---- phase bodies (shared by fused kernel and fallback kernels) ------------

__device__ __forceinline__ void phase_wprep(const Params& P, int bid, int tid)
{
  if (bid < 8) {
    prep_w128_block(P.w_rel1, bid * 32, tid, P.wbr1, P.m_r1);
  } else if (bid < 16) {
    prep_w128_block(P.w_root1, (bid - 8) * 32, tid, P.wbt1, P.m_t1);
  } else if (bid < 32) {
    prep_w256_block(P.w_rel2, (bid - 16) * 4, tid, P.wbr2, P.m_r2);
  } else if (bid < 48) {
    prep_w256_block(P.w_root2, (bid - 32) * 4, tid, P.wbt2, P.m_t2);
  }
}

__device__ __forceinline__ void phase_zero(const Params& P, int gthread, int nthreads)
{
  int cntn = P.N1 + P.N2;
  for (int i = gthread; i < cntn; i += nthreads) P.cnt1[i] = 0;
  int* markw = (int*)P.mark;
  int markn = P.N0 >> 2;
  for (int i = gthread; i < markn; i += nthreads) markw[i] = 0;
}

__device__ __forceinline__ void phase_scatter(const Params& P, int gthread, int nthreads)
{
  int tot = P.E1 + P.E2;
  for (int i = gthread; i < tot; i += nthreads) {
    if (i < P.E1) {
      int s = P.src1[i];
      P.mark[s] = 1;                      // racing same-value stores: fine
      int dd = P.dst1[i];
      int p = atomicAdd(&P.cnt1[dd], 1);
      if (p < CAP1) P.slots1[(size_t)dd * CAP1 + p] = s;
    } else {
      int j = i - P.E1;
      int dd = P.dst2[j];
      int p = atomicAdd(&P.cnt2[dd], 1);
      if (p < CAP2) P.slots2[(size_t)dd * CAP2 + p] = P.src2[j];
    }
  }
}

// 8 rows per wave-job, 16 elems/lane; rec stride 32B: {b0,b1, alpha, pad}
__device__ __forceinline__ void phase_binact(const Params& P, int waveId, int nWaves, int lane)
{
  int njobs = P.N0 >> 3;
  int g = lane >> 3, c = lane & 7;
  for (int j = waveId; j < njobs; j += nWaves) {
    int row = j * 8 + g;
    if (row < P.N1 || P.mark[row] != 0) {   // uniform within 8-lane group
      const nfloat4* xr = (const nfloat4*)(P.x + (size_t)row * 128);
      nfloat4 n0 = __builtin_nontemporal_load(xr + c);
      nfloat4 n1v = __builtin_nontemporal_load(xr + c + 8);
      nfloat4 n2 = __builtin_nontemporal_load(xr + c + 16);
      nfloat4 n3 = __builtin_nontemporal_load(xr + c + 24);
      float4 v0 = make_float4(n0.x, n0.y, n0.z, n0.w);
      float4 v1 = make_float4(n1v.x, n1v.y, n1v.z, n1v.w);
      float4 v2 = make_float4(n2.x, n2.y, n2.z, n2.w);
      float4 v3 = make_float4(n3.x, n3.y, n3.z, n3.w);

      float s = (v0.x + v0.y + v0.z + v0.w) + (v1.x + v1.y + v1.z + v1.w)
              + (v2.x + v2.y + v2.z + v2.w) + (v3.x + v3.y + v3.z + v3.w);
      s += __shfl_xor(s, 1); s += __shfl_xor(s, 2); s += __shfl_xor(s, 4);
      float mu = s * (1.0f / 128.0f);

      float ss = 0.f, sa = 0.f;
      {
        float d;
        d = v0.x - mu; ss += d * d; sa += fabsf(d);
        d = v0.y - mu; ss += d * d; sa += fabsf(d);
        d = v0.z - mu; ss += d * d; sa += fabsf(d);
        d = v0.w - mu; ss += d * d; sa += fabsf(d);
        d = v1.x - mu; ss += d * d; sa += fabsf(d);
        d = v1.y - mu; ss += d * d; sa += fabsf(d);
        d = v1.z - mu; ss += d * d; sa += fabsf(d);
        d = v1.w - mu; ss += d * d; sa += fabsf(d);
        d = v2.x - mu; ss += d * d; sa += fabsf(d);
        d = v2.y - mu; ss += d * d; sa += fabsf(d);
        d = v2.z - mu; ss += d * d; sa += fabsf(d);
        d = v2.w - mu; ss += d * d; sa += fabsf(d);
        d = v3.x - mu; ss += d * d; sa += fabsf(d);
        d = v3.y - mu; ss += d * d; sa += fabsf(d);
        d = v3.z - mu; ss += d * d; sa += fabsf(d);
        d = v3.w - mu; ss += d * d; sa += fabsf(d);
      }
      ss += __shfl_xor(ss, 1); ss += __shfl_xor(ss, 2); ss += __shfl_xor(ss, 4);
      sa += __shfl_xor(sa, 1); sa += __shfl_xor(sa, 2); sa += __shfl_xor(sa, 4);
      float sd = sqrtf(ss * (1.0f / 127.0f));          // ddof=1
      float a  = __fdividef(sa * (1.0f / 128.0f), sd + 1e-4f);

      u64 w0, w1;
      pack_row128(v0, v1, v2, v3, mu, c, w0, w1);
      if (c == 0) {
        u64* rp = P.rec + (size_t)row * 4;
        *(ulonglong2*)rp = make_ulonglong2(w0, w1);
        ((float*)rp)[4] = a;
      }
    }
  }
}

// wave per node; lane owns features f=j*64+lane; per-edge loads wave-uniform.
__device__ __forceinline__ void phase_layer1(const Params& P, int waveId, int nWaves, int lane)
{
  ulonglong2 wr[4], wt[4];
  float mr[4], br[4], mt[4], bt[4];
  #pragma unroll
  for (int j = 0; j < 4; j++) {
    int f = j * 64 + lane;
    wr[j] = P.wbr1[f]; mr[j] = P.m_r1[f]; br[j] = P.b_rel1[f];
    wt[j] = P.wbt1[f]; mt[j] = P.m_t1[f]; bt[j] = P.b_root1[f];
  }
  for (int d = waveId; d < P.N1; d += nWaves) {
    int deg = P.cnt1[d];
    int degc = min(deg, CAP1);
    const int* slot = P.slots1 + (size_t)d * CAP1;

    float acc2[4] = {0.f, 0.f, 0.f, 0.f};
    float suma = 0.f;
    #pragma unroll 4
    for (int e = 0; e < degc; e++) {
      int sn = __builtin_amdgcn_readfirstlane(slot[e]);
      const u64* rp = P.rec + (size_t)sn * 4;   // one 32B line
      ulonglong2 bb = *(const ulonglong2*)rp;
      float a = ((const float*)rp)[4];
      suma += a;
      #pragma unroll
      for (int j = 0; j < 4; j++) {
        int pc = __popcll(bb.x ^ wr[j].x) + __popcll(bb.y ^ wr[j].y);
        acc2[j] += a * (float)pc;
      }
    }

    const u64* rd = P.rec + (size_t)d * 4;      // root row (d < N1 always on)
    ulonglong2 xb = *(const ulonglong2*)rd;
    float ax = ((const float*)rd)[4];

    float invc = (deg > 0) ? 1.0f / (float)deg : 1.0f;
    float z[4];
    #pragma unroll
    for (int j = 0; j < 4; j++) {
      int pcr = __popcll(xb.x ^ wt[j].x) + __popcll(xb.y ^ wt[j].y);
      float rel = mr[j] * (128.0f * suma - 2.0f * acc2[j]) * invc + br[j];
      float rot = mt[j] * ax * (float)(128 - 2 * pcr) + bt[j];
      z[j] = fmaxf(rel + rot, 0.0f);            // relu
    }

    // fused bin_act over this node's 256 z values
    float s = z[0] + z[1] + z[2] + z[3];
    #pragma unroll
    for (int off = 1; off < 64; off <<= 1) s += __shfl_xor(s, off);
    float mu = s * (1.0f / 256.0f);
    float ss = 0.f, sa = 0.f;
    #pragma unroll
    for (int j = 0; j < 4; j++) {
      float dv = z[j] - mu;
      ss += dv * dv; sa += fabsf(dv);
    }
    #pragma unroll
    for (int off = 1; off < 64; off <<= 1) {
      ss += __shfl_xor(ss, off);
      sa += __shfl_xor(sa, off);
    }
    float sd = sqrtf(ss * (1.0f / 255.0f));     // ddof=1
    float a2 = __fdividef(sa * (1.0f / 256.0f), sd + 1e-4f);
    u64 wd0 = __ballot(z[0] > mu);              // word j bit l = feat j*64+l
    u64 wd1 = __ballot(z[1] > mu);
    u64 wd2 = __ballot(z[2] > mu);
    u64 wd3 = __ballot(z[3] > mu);
    if (lane == 0) {
      ulonglong2* bp = (ulonglong2*)(P.bits2 + (size_t)d * 4);
      bp[0] = make_ulonglong2(wd0, wd1);
      bp[1] = make_ulonglong2(wd2, wd3);
      P.alpha2[d] = a2;
    }
  }
}

// wave per node; lane o = output class (OUT=64)
__device__ __forceinline__ void phase_layer2(const Params& P, int waveId, int nWaves, int lane)
{
  int o = lane;
  u64 w0 = P.wbr2[o * 4 + 0], w1 = P.wbr2[o * 4 + 1];
  u64 w2 = P.wbr2[o * 4 + 2], w3 = P.wbr2[o * 4 + 3];
  u64 t0 = P.wbt2[o * 4 + 0], t1 = P.wbt2[o * 4 + 1];
  u64 t2 = P.wbt2[o * 4 + 2], t3 = P.wbt2[o * 4 + 3];
  float mrel = P.m_r2[o], brel = P.b_rel2[o];
  float mrot = P.m_t2[o], brot = P.b_root2[o];
  for (int d = waveId; d < P.N2; d += nWaves) {
    int deg = P.cnt2[d];
    int degc = min(deg, CAP2);
    const int* slot = P.slots2 + (size_t)d * CAP2;
    float acc = 0.0f;
    #pragma unroll 2
    for (int e = 0; e < degc; e++) {
      int sn = __builtin_amdgcn_readfirstlane(slot[e]);
      const ulonglong2* bp = (const ulonglong2*)(P.bits2 + (size_t)sn * 4);
      ulonglong2 p0 = bp[0], p1 = bp[1];
      float a = P.alpha2[sn];
      int pc = __popcll(p0.x ^ w0) + __popcll(p0.y ^ w1)
             + __popcll(p1.x ^ w2) + __popcll(p1.y ^ w3);
      acc += a * (float)(256 - 2 * pc);
    }
    float invc = 1.0f / (float)(deg > 0 ? deg : 1);
    const u64* xp = P.bits2 + (size_t)d * 4;
    float ax = P.alpha2[d];
    int pcr = __popcll(xp[0] ^ t0) + __popcll(xp[1] ^ t1)
            + __popcll(xp[2] ^ t2) + __popcll(xp[3] ^ t3);
    float z = mrel * acc * invc + brel
            + mrot * ax * (float)(256 - 2 * pcr) + brot;
    float mx = z;
    #pragma unroll
    for (int off = 32; off > 0; off >>= 1) mx = fmaxf(mx, __shfl_xor(mx, off));
    float ex = expf(z - mx);
    float se = ex;
    #pragma unroll
    for (int off = 32; off > 0; off >>= 1) se += __shfl_xor(se, off);
    P.out[(size_t)d * 64 + o] = z - mx - logf(se);
  }
}

// ---- fused cooperative kernel ----------------------------------------------
__global__ __launch_bounds__(NTHR, 2) void fused_kernel(Params P)
{
  cg::grid_group grid = cg::this_grid();
  const int tid = threadIdx.x;
  const int bid = blockIdx.x;
  const int gthread = bid * NTHR + tid;
  const int nthreads = NBLK * NTHR;
  const int lane = tid & 63;
  const int waveId = gthread >> 6;
  const int nWaves = nthreads >> 6;

  phase_wprep(P, bid, tid);
  phase_zero(P, gthread, nthreads);
  __threadfence(); grid.sync(); __threadfence();
  phase_scatter(P, gthread, nthreads);
  __threadfence(); grid.sync(); __threadfence();
  phase_binact(P, waveId, nWaves, lane);
  __threadfence(); grid.sync(); __threadfence();
  phase_layer1(P, waveId, nWaves, lane);
  __threadfence(); grid.sync(); __threadfence();
  phase_layer2(P, waveId, nWaves, lane);
}

// ---- fallback kernels (round-4 verified structure, same phase bodies) ------
__global__ __launch_bounds__(NTHR) void k_prep(Params P)
{
  phase_wprep(P, blockIdx.x, threadIdx.x);
  phase_zero(P, blockIdx.x * NTHR + threadIdx.x, gridDim.x * NTHR);
}
__global__ __launch_bounds__(NTHR) void k_scatter(Params P)
{
  phase_scatter(P, blockIdx.x * NTHR + threadIdx.x, gridDim.x * NTHR);
}
__global__ __launch_bounds__(NTHR) void k_binact(Params P)
{
  int g = blockIdx.x * NTHR + threadIdx.x;
  phase_binact(P, g >> 6, (gridDim.x * NTHR) >> 6, threadIdx.x & 63);
}
__global__ __launch_bounds__(NTHR) void k_layer1(Params P)
{
  int g = blockIdx.x * NTHR + threadIdx.x;
  phase_layer1(P, g >> 6, (gridDim.x * NTHR) >> 6, threadIdx.x & 63);
}
__global__ __launch_bounds__(NTHR) void k_layer2(Params P)
{
  int g = blockIdx.x * NTHR + threadIdx.x;
  phase_layer2(P, g >> 6, (gridDim.x * NTHR) >> 6, threadIdx.x & 63);
}

// ---------------------------------------------------------------------------
extern "C" void kernel_launch(void* const* d_in, const int* in_sizes, int n_in,
                              void* d_out, int out_size, void* d_ws, size_t ws_size,
                              hipStream_t stream)
{
  const int IN  = 128;
  const int HID = in_sizes[6];            // 256
  const int OUT = in_sizes[10];           // 64
  const int N0  = in_sizes[0] / IN;       // 512000
  const int E1  = in_sizes[1];            // 512000
  const int E2  = in_sizes[3];            // 20480
  const int N1  = 20480;                  // n1 (fixed shape for this problem)
  const int N2  = out_size / OUT;         // 2048
  (void)n_in; (void)ws_size;

  char* p = (char*)d_ws;
  auto alloc = [&](size_t bytes) {
    char* r = p;
    p += (bytes + 255) & ~(size_t)255;
    return r;
  };
  u64*   rec    = (u64*)alloc((size_t)N0 * 32);             // 16.4 MB
  u64*   bits2  = (u64*)alloc((size_t)N1 * 32);
  float* alpha2 = (float*)alloc((size_t)N1 * 4);
  int*   slots1 = (int*)alloc((size_t)N1 * CAP1 * 4);       // 10.5 MB
  int*   slots2 = (int*)alloc((size_t)N2 * CAP2 * 4);       // 1.0 MB
  int*   cnt1   = (int*)alloc((size_t)(N1 + N2) * 4);
  int*   cnt2   = cnt1 + N1;
  unsigned char* mark = (unsigned char*)alloc((size_t)N0);  // 512 KB
  ulonglong2* wbr1 = (ulonglong2*)alloc((size_t)HID * 16);
  ulonglong2* wbt1 = (ulonglong2*)alloc((size_t)HID * 16);
  u64*   wbr2   = (u64*)alloc((size_t)OUT * 32);
  u64*   wbt2   = (u64*)alloc((size_t)OUT * 32);
  float* m_r1   = (float*)alloc((size_t)HID * 4);
  float* m_t1   = (float*)alloc((size_t)HID * 4);
  float* m_r2   = (float*)alloc((size_t)OUT * 4);
  float* m_t2   = (float*)alloc((size_t)OUT * 4);

  Params P;
  P.x = (const float*)d_in[0];
  P.src1 = (const int*)d_in[1];
  P.dst1 = (const int*)d_in[2];
  P.src2 = (const int*)d_in[3];
  P.dst2 = (const int*)d_in[4];
  P.w_rel1 = (const float*)d_in[5];
  P.b_rel1 = (const float*)d_in[6];
  P.w_root1 = (const float*)d_in[7];
  P.b_root1 = (const float*)d_in[8];
  P.w_rel2 = (const float*)d_in[9];
  P.b_rel2 = (const float*)d_in[10];
  P.w_root2 = (const float*)d_in[11];
  P.b_root2 = (const float*)d_in[12];
  P.rec = rec; P.bits2 = bits2; P.alpha2 = alpha2;
  P.slots1 = slots1; P.slots2 = slots2; P.cnt1 = cnt1; P.cnt2 = cnt2;
  P.mark = mark;
  P.wbr1 = wbr1; P.wbt1 = wbt1; P.wbr2 = wbr2; P.wbt2 = wbt2;
  P.m_r1 = m_r1; P.m_t1 = m_t1; P.m_r2 = m_r2; P.m_t2 = m_t2;
  P.out = (float*)d_out;
  P.E1 = E1; P.E2 = E2; P.N0 = N0; P.N1 = N1; P.N2 = N2;

  void* args[] = { &P };
  hipError_t err = hipLaunchCooperativeKernel((const void*)fused_kernel,
                                              dim3(NBLK), dim3(NTHR), args,
                                              0, stream);
  if (err != hipSuccess) {
    // Fallback: round-4 verified 5-dispatch chain (identical phase bodies).
    k_prep   <<<128,                     NTHR, 0, stream>>>(P);
    k_scatter<<<(E1 + E2 + NTHR - 1) / NTHR, NTHR, 0, stream>>>(P);
    k_binact <<<N0 / 32,                 NTHR, 0, stream>>>(P);
    k_layer1 <<<N1 / 4,                  NTHR, 0, stream>>>(P);
    k_layer2 <<<N2 / 4,                  NTHR, 0, stream>>>(P);
  }
}

// Round 7
// 472.626 us; speedup vs baseline: 2.4614x; 2.4614x over previous
//
#include <hip/hip_runtime.h>
#include <stdint.h>

typedef unsigned long long u64;
typedef float nfloat4 __attribute__((ext_vector_type(4)));  // native vec for nontemporal builtins

// ---------------------------------------------------------------------------
// Binarized GraphSAGE, 2 layers — 5 dispatches (round-4 verified structure).
//  Round-7: cooperative fusion (round 6) measured 843 us in-kernel — grid.sync
//  + agent-fence cost ~750 us on this 8-XCD part, 100x the launch overhead it
//  saved. REVERTED to the 458.7-us round-4 chain, plus:
//   * bit-mask mark (u32[N0/32], 64 KB) instead of byte mark (512 KB):
//     8x less zeroing/traffic; scatter uses atomicOr.
//   * root rows (< N1) prefilled as all-ones words during the zero pass ->
//     binact skip test = ONE wave-uniform word load + per-group bit test
//     (no divergent byte gather, no row<N1 branch, uniform whole-wave skip).
//
// Bit layout for 128-wide rows (x rows AND layer1 weight rows — must match;
// guaranteed by sharing pack_row128):
//   element e = (it*8+c)*4+k  ->  word (c>>2), bit 16*(c&3) + it*4 + k
// 256-wide rows (h rows and layer2 weight rows): word (e>>6), bit (e&63).
// ---------------------------------------------------------------------------

#define CAP1 128
#define CAP2 128

// sign-pack one 128-elem row held by an 8-lane group (16 elems/lane), vs mu.
__device__ __forceinline__ void pack_row128(
    float4 v0, float4 v1, float4 v2, float4 v3, float mu, int c,
    u64& w0, u64& w1)
{
  unsigned m = 0;
  m |= (v0.x > mu) ? 1u << 0  : 0u;
  m |= (v0.y > mu) ? 1u << 1  : 0u;
  m |= (v0.z > mu) ? 1u << 2  : 0u;
  m |= (v0.w > mu) ? 1u << 3  : 0u;
  m |= (v1.x > mu) ? 1u << 4  : 0u;
  m |= (v1.y > mu) ? 1u << 5  : 0u;
  m |= (v1.z > mu) ? 1u << 6  : 0u;
  m |= (v1.w > mu) ? 1u << 7  : 0u;
  m |= (v2.x > mu) ? 1u << 8  : 0u;
  m |= (v2.y > mu) ? 1u << 9  : 0u;
  m |= (v2.z > mu) ? 1u << 10 : 0u;
  m |= (v2.w > mu) ? 1u << 11 : 0u;
  m |= (v3.x > mu) ? 1u << 12 : 0u;
  m |= (v3.y > mu) ? 1u << 13 : 0u;
  m |= (v3.z > mu) ? 1u << 14 : 0u;
  m |= (v3.w > mu) ? 1u << 15 : 0u;
  u64 wv = (u64)m << (16 * (c & 3));
  wv |= __shfl_xor(wv, 1);
  wv |= __shfl_xor(wv, 2);
  u64 other = __shfl_xor(wv, 4);
  w0 = (c & 4) ? other : wv;
  w1 = (c & 4) ? wv : other;
}

// pack a 128-wide weight block of rows (8 rows per wave), same layout
__device__ __forceinline__ void prep_w128_block(
    const float* __restrict__ w, int rowbase, int tid,
    ulonglong2* __restrict__ wbits, float* __restrict__ m)
{
  int lane = tid & 63;
  int g = lane >> 3, c = lane & 7;
  int row = rowbase + (tid >> 6) * 8 + g;
  const float4* wr = (const float4*)(w + (size_t)row * 128);
  float4 v0 = wr[c];
  float4 v1 = wr[c + 8];
  float4 v2 = wr[c + 16];
  float4 v3 = wr[c + 24];
  float s = fabsf(v0.x) + fabsf(v0.y) + fabsf(v0.z) + fabsf(v0.w)
          + fabsf(v1.x) + fabsf(v1.y) + fabsf(v1.z) + fabsf(v1.w)
          + fabsf(v2.x) + fabsf(v2.y) + fabsf(v2.z) + fabsf(v2.w)
          + fabsf(v3.x) + fabsf(v3.y) + fabsf(v3.z) + fabsf(v3.w);
  s += __shfl_xor(s, 1); s += __shfl_xor(s, 2); s += __shfl_xor(s, 4);
  u64 w0, w1;
  pack_row128(v0, v1, v2, v3, 0.0f, c, w0, w1);
  if (c == 0) {
    wbits[row] = make_ulonglong2(w0, w1);
    m[row] = s * (1.0f / 128.0f);
  }
}

// pack a 256-wide weight block (1 row per wave, 4 rows per 256-thr block)
__device__ __forceinline__ void prep_w256_block(
    const float* __restrict__ w, int rowbase, int tid,
    u64* __restrict__ wbits, float* __restrict__ m)
{
  int lane = tid & 63;
  int o = rowbase + (tid >> 6);
  const float* wr = w + (size_t)o * 256;
  float s = 0.0f;
  u64 b[4];
  #pragma unroll
  for (int wd = 0; wd < 4; wd++) {
    float v = wr[wd * 64 + lane];
    s += fabsf(v);
    b[wd] = __ballot(v > 0.0f);
  }
  #pragma unroll
  for (int off = 32; off > 0; off >>= 1) s += __shfl_xor(s, off);
  if (lane == 0) {
    wbits[o * 4 + 0] = b[0]; wbits[o * 4 + 1] = b[1];
    wbits[o * 4 + 2] = b[2]; wbits[o * 4 + 3] = b[3];
    m[o] = s * (1.0f / 256.0f);
  }
}

// ---- dispatch 1: weight packs + zero cnt + init mark words -----------------
// blocks 0..7: w_rel1 | 8..15: w_root1 | 16..31: w_rel2 | 32..47: w_root2;
// ALL blocks also grid-stride the zero/init sweep (tiny: 22528 + 16000 words)
__global__ __launch_bounds__(256) void prep_all_kernel(
    const float* __restrict__ w_rel1, const float* __restrict__ w_root1,
    const float* __restrict__ w_rel2, const float* __restrict__ w_root2,
    ulonglong2* __restrict__ wbr1, float* __restrict__ m_r1,
    ulonglong2* __restrict__ wbt1, float* __restrict__ m_t1,
    u64* __restrict__ wbr2, float* __restrict__ m_r2,
    u64* __restrict__ wbt2, float* __restrict__ m_t2,
    int* __restrict__ cnt, int cntn,
    unsigned* __restrict__ markw, int markn, int rootw)
{
  int b = blockIdx.x, t = threadIdx.x;
  if (b < 8) {
    prep_w128_block(w_rel1, b * 32, t, wbr1, m_r1);
  } else if (b < 16) {
    prep_w128_block(w_root1, (b - 8) * 32, t, wbt1, m_t1);
  } else if (b < 32) {
    prep_w256_block(w_rel2, (b - 16) * 4, t, wbr2, m_r2);
  } else if (b < 48) {
    prep_w256_block(w_root2, (b - 32) * 4, t, wbt2, m_t2);
  }
  int gthread = b * 256 + t;
  int nthreads = gridDim.x * 256;
  for (int i = gthread; i < cntn; i += nthreads) cnt[i] = 0;
  for (int i = gthread; i < markn; i += nthreads)
    markw[i] = (i < rootw) ? 0xFFFFFFFFu : 0u;   // roots always "marked"
}

// ---- dispatch 2: direct-slot scatter for BOTH graphs + bit-mark src rows ---
__global__ void scatter_direct_kernel(
    const int* __restrict__ dst1, const int* __restrict__ src1, int E1,
    int* __restrict__ cnt1, int* __restrict__ slots1,
    const int* __restrict__ dst2, const int* __restrict__ src2, int E2,
    int* __restrict__ cnt2, int* __restrict__ slots2,
    unsigned* __restrict__ markw)
{
  int i = blockIdx.x * blockDim.x + threadIdx.x;
  if (i < E1) {
    int s = src1[i];
    atomicOr(&markw[s >> 5], 1u << (s & 31));
    int dd = dst1[i];
    int p = atomicAdd(&cnt1[dd], 1);
    if (p < CAP1) slots1[(size_t)dd * CAP1 + p] = s;
  } else if (i < E1 + E2) {
    int j = i - E1;
    int dd = dst2[j];
    int p = atomicAdd(&cnt2[dd], 1);
    if (p < CAP2) slots2[(size_t)dd * CAP2 + p] = src2[j];
  }
}

// ---- dispatch 3: bin_act(x), marked rows only ------------------------------
// 8 rows/wave, 16 elems/lane; rec stride 32B: {b0,b1, alpha, pad}.
// Skip test: one wave-uniform mark word, per-8-lane-group bit test.
__global__ __launch_bounds__(256) void binact128_kernel(
    const float* __restrict__ x, const unsigned* __restrict__ markw,
    u64* __restrict__ rec)
{
  int lane = threadIdx.x & 63;
  int wid  = blockIdx.x * 4 + (threadIdx.x >> 6);
  int g = lane >> 3;           // row within wave's 8-row group
  int c = lane & 7;            // column chunk
  int row0 = wid * 8;          // job base; all 8 rows' bits in ONE word
  unsigned mbyte = (markw[row0 >> 5] >> (row0 & 31)) & 0xFFu;
  if (mbyte == 0) return;                    // uniform whole-wave skip
  if (((mbyte >> g) & 1u) == 0) return;      // per-group skip (predicated)
  int row = row0 + g;

  const nfloat4* xr = (const nfloat4*)(x + (size_t)row * 128);
  nfloat4 n0 = __builtin_nontemporal_load(xr + c);
  nfloat4 n1v = __builtin_nontemporal_load(xr + c + 8);
  nfloat4 n2 = __builtin_nontemporal_load(xr + c + 16);
  nfloat4 n3 = __builtin_nontemporal_load(xr + c + 24);
  float4 v0 = make_float4(n0.x, n0.y, n0.z, n0.w);
  float4 v1 = make_float4(n1v.x, n1v.y, n1v.z, n1v.w);
  float4 v2 = make_float4(n2.x, n2.y, n2.z, n2.w);
  float4 v3 = make_float4(n3.x, n3.y, n3.z, n3.w);

  float s = (v0.x + v0.y + v0.z + v0.w) + (v1.x + v1.y + v1.z + v1.w)
          + (v2.x + v2.y + v2.z + v2.w) + (v3.x + v3.y + v3.z + v3.w);
  s += __shfl_xor(s, 1); s += __shfl_xor(s, 2); s += __shfl_xor(s, 4);
  float mu = s * (1.0f / 128.0f);

  float ss = 0.f, sa = 0.f;
  {
    float d;
    d = v0.x - mu; ss += d * d; sa += fabsf(d);
    d = v0.y - mu; ss += d * d; sa += fabsf(d);
    d = v0.z - mu; ss += d * d; sa += fabsf(d);
    d = v0.w - mu; ss += d * d; sa += fabsf(d);
    d = v1.x - mu; ss += d * d; sa += fabsf(d);
    d = v1.y - mu; ss += d * d; sa += fabsf(d);
    d = v1.z - mu; ss += d * d; sa += fabsf(d);
    d = v1.w - mu; ss += d * d; sa += fabsf(d);
    d = v2.x - mu; ss += d * d; sa += fabsf(d);
    d = v2.y - mu; ss += d * d; sa += fabsf(d);
    d = v2.z - mu; ss += d * d; sa += fabsf(d);
    d = v2.w - mu; ss += d * d; sa += fabsf(d);
    d = v3.x - mu; ss += d * d; sa += fabsf(d);
    d = v3.y - mu; ss += d * d; sa += fabsf(d);
    d = v3.z - mu; ss += d * d; sa += fabsf(d);
    d = v3.w - mu; ss += d * d; sa += fabsf(d);
  }
  ss += __shfl_xor(ss, 1); ss += __shfl_xor(ss, 2); ss += __shfl_xor(ss, 4);
  sa += __shfl_xor(sa, 1); sa += __shfl_xor(sa, 2); sa += __shfl_xor(sa, 4);
  float sd = sqrtf(ss * (1.0f / 127.0f));            // ddof=1
  float a  = __fdividef(sa * (1.0f / 128.0f), sd + 1e-4f);

  u64 w0, w1;
  pack_row128(v0, v1, v2, v3, mu, c, w0, w1);
  if (c == 0) {
    u64* rp = rec + (size_t)row * 4;
    *(ulonglong2*)rp = make_ulonglong2(w0, w1);
    ((float*)rp)[4] = a;
  }
}

// ---- dispatch 4: layer 1 — scalar-load edges, popcount, relu, binact(h) ----
// one WAVE per dst node (4 waves/block); lane owns features f = j*64+lane.
// Per edge everything loaded is wave-uniform: no cross-lane ops at all.
__global__ __launch_bounds__(256) void layer1_kernel(
    const u64* __restrict__ rec,
    const int* __restrict__ cnt, const int* __restrict__ slots,
    const ulonglong2* __restrict__ wb_rel, const float* __restrict__ m_rel,
    const float* __restrict__ b_rel,
    const ulonglong2* __restrict__ wb_root, const float* __restrict__ m_root,
    const float* __restrict__ b_root,
    u64* __restrict__ bits2, float* __restrict__ alpha2)
{
  int lane = threadIdx.x & 63;
  int d = blockIdx.x * 4 + (threadIdx.x >> 6);

  ulonglong2 wr[4], wt[4];
  float mr[4], br[4], mt[4], bt[4];
  #pragma unroll
  for (int j = 0; j < 4; j++) {
    int f = j * 64 + lane;
    wr[j] = wb_rel[f];  mr[j] = m_rel[f];  br[j] = b_rel[f];
    wt[j] = wb_root[f]; mt[j] = m_root[f]; bt[j] = b_root[f];
  }

  int deg = cnt[d];
  int degc = min(deg, CAP1);
  const int* slot = slots + (size_t)d * CAP1;

  float acc2[4] = {0.f, 0.f, 0.f, 0.f};   // sum over edges of a * popc
  float suma = 0.f;                       // sum over edges of a

  #pragma unroll 4
  for (int e = 0; e < degc; e++) {
    int sn = __builtin_amdgcn_readfirstlane(slot[e]);
    const u64* rp = rec + (size_t)sn * 4;  // one 32B line: bits + alpha
    ulonglong2 bb = *(const ulonglong2*)rp;
    float a = ((const float*)rp)[4];
    suma += a;
    #pragma unroll
    for (int j = 0; j < 4; j++) {
      int pc = __popcll(bb.x ^ wr[j].x) + __popcll(bb.y ^ wr[j].y);
      acc2[j] += a * (float)pc;
    }
  }

  // root term: xt = bin_act(x[d]) precomputed (d < N1, always marked)
  const u64* rd = rec + (size_t)d * 4;
  ulonglong2 xb = *(const ulonglong2*)rd;
  float ax = ((const float*)rd)[4];

  float invc = (deg > 0) ? 1.0f / (float)deg : 1.0f;
  float z[4];
  #pragma unroll
  for (int j = 0; j < 4; j++) {
    int pcr = __popcll(xb.x ^ wt[j].x) + __popcll(xb.y ^ wt[j].y);
    float rel = mr[j] * (128.0f * suma - 2.0f * acc2[j]) * invc + br[j];
    float rot = mt[j] * ax * (float)(128 - 2 * pcr) + bt[j];
    z[j] = fmaxf(rel + rot, 0.0f);        // relu
  }

  // fused bin_act over this node's 256 z values (once per NODE — cheap)
  float s = z[0] + z[1] + z[2] + z[3];
  #pragma unroll
  for (int off = 1; off < 64; off <<= 1) s += __shfl_xor(s, off);
  float mu = s * (1.0f / 256.0f);
  float ss = 0.f, sa = 0.f;
  #pragma unroll
  for (int j = 0; j < 4; j++) {
    float dv = z[j] - mu;
    ss += dv * dv; sa += fabsf(dv);
  }
  #pragma unroll
  for (int off = 1; off < 64; off <<= 1) {
    ss += __shfl_xor(ss, off);
    sa += __shfl_xor(sa, off);
  }
  float sd = sqrtf(ss * (1.0f / 255.0f));  // ddof=1
  float a2 = __fdividef(sa * (1.0f / 256.0f), sd + 1e-4f);
  u64 wd0 = __ballot(z[0] > mu);           // word j bit l = feature j*64+l
  u64 wd1 = __ballot(z[1] > mu);
  u64 wd2 = __ballot(z[2] > mu);
  u64 wd3 = __ballot(z[3] > mu);
  if (lane == 0) {
    ulonglong2* bp = (ulonglong2*)(bits2 + (size_t)d * 4);
    bp[0] = make_ulonglong2(wd0, wd1);
    bp[1] = make_ulonglong2(wd2, wd3);
    alpha2[d] = a2;
  }
}

// ---- dispatch 5: layer 2 — scalar-load edges + bin_linears + log_softmax ---
// one wave per dst node, 4 waves/block; lane o computes output class o (OUT=64)
__global__ __launch_bounds__(256) void layer2_kernel(
    const u64* __restrict__ bits2, const float* __restrict__ alpha2,
    const int* __restrict__ cnt, const int* __restrict__ slots,
    const u64* __restrict__ wb_rel, const float* __restrict__ m_rel,
    const float* __restrict__ b_rel,
    const u64* __restrict__ wb_root, const float* __restrict__ m_root,
    const float* __restrict__ b_root,
    float* __restrict__ out)
{
  int d = blockIdx.x * 4 + (threadIdx.x >> 6);
  int o = threadIdx.x & 63;
  u64 w0 = wb_rel[o * 4 + 0], w1 = wb_rel[o * 4 + 1];
  u64 w2 = wb_rel[o * 4 + 2], w3 = wb_rel[o * 4 + 3];
  int deg = cnt[d];
  int degc = min(deg, CAP2);
  const int* slot = slots + (size_t)d * CAP2;
  float acc = 0.0f;
  #pragma unroll 2
  for (int e = 0; e < degc; e++) {
    int sn = __builtin_amdgcn_readfirstlane(slot[e]);
    const ulonglong2* bp = (const ulonglong2*)(bits2 + (size_t)sn * 4);
    ulonglong2 p0 = bp[0], p1 = bp[1];    // wave-uniform 32 B
    float a = alpha2[sn];
    int pc = __popcll(p0.x ^ w0) + __popcll(p0.y ^ w1)
           + __popcll(p1.x ^ w2) + __popcll(p1.y ^ w3);
    acc += a * (float)(256 - 2 * pc);
  }
  float invc = 1.0f / (float)(deg > 0 ? deg : 1);
  const u64* xp = bits2 + (size_t)d * 4;   // xt2 = bin_act(h[:n2]) row d
  float ax = alpha2[d];
  int pcr = __popcll(xp[0] ^ wb_root[o * 4 + 0]) + __popcll(xp[1] ^ wb_root[o * 4 + 1])
          + __popcll(xp[2] ^ wb_root[o * 4 + 2]) + __popcll(xp[3] ^ wb_root[o * 4 + 3]);
  float z = m_rel[o] * acc * invc + b_rel[o]
          + m_root[o] * ax * (float)(256 - 2 * pcr) + b_root[o];
  // log_softmax over the 64 classes (one wave)
  float mx = z;
  #pragma unroll
  for (int off = 32; off > 0; off >>= 1) mx = fmaxf(mx, __shfl_xor(mx, off));
  float ex = expf(z - mx);
  float se = ex;
  #pragma unroll
  for (int off = 32; off > 0; off >>= 1) se += __shfl_xor(se, off);
  out[(size_t)d * 64 + o] = z - mx - logf(se);
}

// ---------------------------------------------------------------------------
extern "C" void kernel_launch(void* const* d_in, const int* in_sizes, int n_in,
                              void* d_out, int out_size, void* d_ws, size_t ws_size,
                              hipStream_t stream)
{
  const float* x       = (const float*)d_in[0];
  const int*   src1    = (const int*)d_in[1];
  const int*   dst1    = (const int*)d_in[2];
  const int*   src2    = (const int*)d_in[3];
  const int*   dst2    = (const int*)d_in[4];
  const float* w_rel1  = (const float*)d_in[5];
  const float* b_rel1  = (const float*)d_in[6];
  const float* w_root1 = (const float*)d_in[7];
  const float* b_root1 = (const float*)d_in[8];
  const float* w_rel2  = (const float*)d_in[9];
  const float* b_rel2  = (const float*)d_in[10];
  const float* w_root2 = (const float*)d_in[11];
  const float* b_root2 = (const float*)d_in[12];

  const int IN  = 128;
  const int HID = in_sizes[6];            // 256
  const int OUT = in_sizes[10];           // 64
  const int N0  = in_sizes[0] / IN;       // 512000
  const int E1  = in_sizes[1];            // 512000
  const int E2  = in_sizes[3];            // 20480
  const int N1  = 20480;                  // n1 (fixed shape for this problem)
  const int N2  = out_size / OUT;         // 2048
  (void)n_in; (void)ws_size;

  char* p = (char*)d_ws;
  auto alloc = [&](size_t bytes) {
    char* r = p;
    p += (bytes + 255) & ~(size_t)255;
    return r;
  };
  u64*   rec    = (u64*)alloc((size_t)N0 * 32);             // 16.4 MB
  u64*   bits2  = (u64*)alloc((size_t)N1 * 32);
  float* alpha2 = (float*)alloc((size_t)N1 * 4);
  int*   slots1 = (int*)alloc((size_t)N1 * CAP1 * 4);       // 10.5 MB
  int*   slots2 = (int*)alloc((size_t)N2 * CAP2 * 4);       // 1.0 MB
  int*   cnt1   = (int*)alloc((size_t)(N1 + N2) * 4);
  int*   cnt2   = cnt1 + N1;
  unsigned* markw = (unsigned*)alloc((size_t)(N0 / 32) * 4); // 64 KB
  ulonglong2* wbr1 = (ulonglong2*)alloc((size_t)HID * 16);
  ulonglong2* wbt1 = (ulonglong2*)alloc((size_t)HID * 16);
  u64*   wbr2   = (u64*)alloc((size_t)OUT * 32);
  u64*   wbt2   = (u64*)alloc((size_t)OUT * 32);
  float* m_r1   = (float*)alloc((size_t)HID * 4);
  float* m_t1   = (float*)alloc((size_t)HID * 4);
  float* m_r2   = (float*)alloc((size_t)OUT * 4);
  float* m_t2   = (float*)alloc((size_t)OUT * 4);

  // 1) weight preps + zero counters + init mark words (48 blocks)
  prep_all_kernel<<<48, 256, 0, stream>>>(
      w_rel1, w_root1, w_rel2, w_root2,
      wbr1, m_r1, wbt1, m_t1, wbr2, m_r2, wbt2, m_t2,
      cnt1, N1 + N2, markw, N0 / 32, N1 / 32);

  // 2) direct-slot scatter for both graphs + bit-mark used x rows
  scatter_direct_kernel<<<(E1 + E2 + 255) / 256, 256, 0, stream>>>(
      dst1, src1, E1, cnt1, slots1, dst2, src2, E2, cnt2, slots2, markw);

  // 3) binarize referenced x rows (exact grid: N0 % 32 == 0)
  binact128_kernel<<<N0 / 32, 256, 0, stream>>>(x, markw, rec);

  // 4) layer 1 (scalar-load edges + popc linears + relu + binact)
  layer1_kernel<<<N1 / 4, 256, 0, stream>>>(rec, cnt1, slots1,
                                            wbr1, m_r1, b_rel1, wbt1, m_t1, b_root1,
                                            bits2, alpha2);

  // 5) layer 2 (scalar-load edges + linears + log_softmax)
  layer2_kernel<<<N2 / 4, 256, 0, stream>>>(bits2, alpha2, cnt2, slots2,
                                            wbr2, m_r2, b_rel2, wbt2, m_t2, b_root2,
                                            (float*)d_out);
}